// Round 17
// baseline (1541.432 us; speedup 1.0000x reference)
//
#include <hip/hip_runtime.h>

// ---------------- problem constants ----------------
#define TPB   256
#define NWG   512
#define SEQL  200
#define BATCH 64
#define EDIM  300
#define HDIM  512
#define ODIM  5
#define NROW  (4*HDIM)   // 2048 gate rows

// ---------------- group decomposition ----------------
#define GROUPS 16     // independent batch groups (group = blockIdx & 15)
#define GB     4      // batch rows per group
#define UNITS  16     // h units per block

// ---------------- persist-kernel LDS layout (word offsets) ----------------
// [0..2048)      h tile [512 k][4 b]; phys = (4k ^ (((k>>5)&3)<<2)) + b
// [2048..10880)  ex[2 par][64 r][4 b][17]  (parity double-buffer, no B2)
// [10880..12080) embT[300][4] (fallback only)
#define EX_OFF   2048
#define EX_RSTR  69
#define EX_BSTR  17
#define EX_PAR   (64 * EX_RSTR)              // 4416 words per parity
#define EMB_OFF  (EX_OFF + 2 * EX_PAR)       // 10880
#define LDS_BYTES 56320                      // 55 KiB: 2 blocks/CU fit, 3 don't

// ---------------- tagged h exchange ----------------
#define HT_GROUP 2048
#define HT_PAR   (GROUPS * HT_GROUP)               // 32768 ull per parity
#define HT_BYTES (2 * HT_PAR * 8)                  // 512 KiB

// ---------------- precompute-kernel LDS (half-batch: 32 rows) ----------------
#define ESTR 308
#define PRE_LDS_BYTES (32 * ESTR * 4)        // 39424 B -> 4 blocks/CU

#define GATES_FLOATS ((size_t)SEQL * NROW * BATCH)   // 104.9 MB
#define WT_FLOATS    ((size_t)EDIM * NROW)           // 614400 (2.4 MB)

__device__ __forceinline__ float fast_sigmoid(float x) {
    return 1.0f / (1.0f + __expf(-x));
}
__device__ __forceinline__ float fast_tanh(float x) {
    return 2.0f / (1.0f + __expf(-2.0f * x)) - 1.0f;
}

// ============================================================================
// W_ih transpose: WT[e][row] = W_ih[row][e].  Tiled 32x32 via LDS.
// ============================================================================
extern "C" __global__ void __launch_bounds__(256)
wih_transpose(const float* __restrict__ W, float* __restrict__ WT)
{
    __shared__ float t[32][33];
    const int r0 = blockIdx.x * 32;
    const int e0 = blockIdx.y * 32;
    const int le = threadIdx.x & 31;
    const int lr = threadIdx.x >> 5;

    for (int rr = lr; rr < 32; rr += 8) {
        const int e = e0 + le;
        t[rr][le] = (e < EDIM) ? W[(size_t)(r0 + rr) * EDIM + e] : 0.0f;
    }
    __syncthreads();
    for (int ee = lr; ee < 32; ee += 8) {
        const int e = e0 + ee;
        if (e < EDIM) WT[(size_t)e * NROW + r0 + le] = t[le][ee];
    }
}

// ============================================================================
// Precompute: gates[s][group][row][4]. Half-batch blocks (32 rows, 4/CU).
// ============================================================================
extern "C" __global__ void __launch_bounds__(256, 4)
lstm_pre(const int* __restrict__ x, const float* __restrict__ emb,
         const float* __restrict__ W_ih, const float* __restrict__ wT,
         float* __restrict__ gates)
{
    extern __shared__ float embs[];          // [32][ESTR]
    const int tid = threadIdx.x;
    const int s   = blockIdx.x >> 4;
    const int rb  = (blockIdx.x >> 1) & 7;
    const int hb  = blockIdx.x & 1;          // batch half

    for (int i = tid; i < 32 * 75; i += 256) {
        int b = i / 75, jj = i - b * 75;
        int row = x[(32 * hb + b) * SEQL + s];
        float4 v = ((const float4*)(emb + (size_t)row * EDIM))[jj];
        *(float4*)&embs[b * ESTR + 4 * jj] = v;
    }
    __syncthreads();

    const int bi = tid >> 6;      // octet within half (0..3) — wave-uniform
    const int ri = tid & 63;
    const int row0 = rb * 256 + ri * 4;

    float acc[4][8];
#pragma unroll
    for (int a = 0; a < 4; a++)
#pragma unroll
        for (int b = 0; b < 8; b++) acc[a][b] = 0.0f;

    if (wT) {
        for (int t2 = 0; t2 < 75; t2++) {
            float4 w[4], e[8];
#pragma unroll
            for (int c = 0; c < 4; c++)
                w[c] = *(const float4*)(wT + (size_t)(4 * t2 + c) * NROW + row0);
#pragma unroll
            for (int bb = 0; bb < 8; bb++)
                e[bb] = *(const float4*)&embs[(bi * 8 + bb) * ESTR + 4 * t2];
#pragma unroll
            for (int c = 0; c < 4; c++) {
#pragma unroll
                for (int bb = 0; bb < 8; bb++) {
                    const float ec = c == 0 ? e[bb].x : c == 1 ? e[bb].y
                                   : c == 2 ? e[bb].z : e[bb].w;
                    acc[0][bb] = fmaf(w[c].x, ec, acc[0][bb]);
                    acc[1][bb] = fmaf(w[c].y, ec, acc[1][bb]);
                    acc[2][bb] = fmaf(w[c].z, ec, acc[2][bb]);
                    acc[3][bb] = fmaf(w[c].w, ec, acc[3][bb]);
                }
            }
        }
    } else {
        const float* wp = W_ih + (size_t)row0 * EDIM;
        for (int t2 = 0; t2 < 75; t2++) {
            float4 w[4], e[8];
#pragma unroll
            for (int rr = 0; rr < 4; rr++)
                w[rr] = *(const float4*)(wp + rr * EDIM + 4 * t2);
#pragma unroll
            for (int bb = 0; bb < 8; bb++)
                e[bb] = *(const float4*)&embs[(bi * 8 + bb) * ESTR + 4 * t2];
#pragma unroll
            for (int rr = 0; rr < 4; rr++)
#pragma unroll
                for (int bb = 0; bb < 8; bb++) {
                    acc[rr][bb] = fmaf(w[rr].x, e[bb].x, acc[rr][bb]);
                    acc[rr][bb] = fmaf(w[rr].y, e[bb].y, acc[rr][bb]);
                    acc[rr][bb] = fmaf(w[rr].z, e[bb].z, acc[rr][bb]);
                    acc[rr][bb] = fmaf(w[rr].w, e[bb].w, acc[rr][bb]);
                }
        }
    }

    float* dstA = gates + (size_t)(s * GROUPS + 8 * hb + 2 * bi)     * 8192 + row0 * 4;
    float* dstB = gates + (size_t)(s * GROUPS + 8 * hb + 2 * bi + 1) * 8192 + row0 * 4;
#pragma unroll
    for (int rr = 0; rr < 4; rr++) {
        *(float4*)(dstA + 4 * rr) = make_float4(acc[rr][0], acc[rr][1], acc[rr][2], acc[rr][3]);
        *(float4*)(dstB + 4 * rr) = make_float4(acc[rr][4], acc[rr][5], acc[rr][6], acc[rr][7]);
    }
}

// ============================================================================
// Persistent LSTM — r12 structure with (a) ex parity double-buffer -> B2
// removed (WAR now ordered by B1(s+1): any ex-write(s+2,p) is behind it,
// and wave 0's cell-read(s,p) precedes it), (b) single-sweep 8-word poll
// (one L3 detection latency instead of two serial rounds).
// ============================================================================
extern "C" __global__ void __launch_bounds__(TPB, 2)
lstm_persist(const int* __restrict__ x, const float* __restrict__ emb,
             const float* __restrict__ W_ih, const float* __restrict__ W_hh,
             const float* __restrict__ b_ih, const float* __restrict__ b_hh,
             const float* __restrict__ gates,      // may be null
             unsigned long long* __restrict__ htag) // [2][16][2048] tagged h
{
    extern __shared__ float lds[];
    const int tid = threadIdx.x;
    const int g   = blockIdx.x & 15;
    const int j   = blockIdx.x >> 4;        // 0..31
    const bool pre = (gates != nullptr);

    const int rq = tid & 15;      // rows 4rq..4rq+3 (r = gate*16+u)
    const int kh = tid >> 4;      // k in [32kh, 32kh+32)
    const int wv = tid >> 6;      // wave 0..3
    const int ln = tid & 63;      // lane

    // ---- W_hh slice -> 128 VGPRs (static indexing only; rule #20) ----
    float4 w4[4][8];
#pragma unroll
    for (int p = 0; p < 4; p++) {
        const int r = 4 * rq + p;
        const size_t R = (size_t)((r >> 4) * HDIM + UNITS * j + (r & 15));
        const float* wp = W_hh + R * HDIM + 32 * kh;
#pragma unroll
        for (int kq = 0; kq < 8; kq++) w4[p][kq] = *(const float4*)(wp + 4 * kq);
    }
#pragma unroll
    for (int p = 0; p < 4; p++)
#pragma unroll
        for (int kq = 0; kq < 8; kq++)
            asm volatile("" : "+v"(w4[p][kq].x), "+v"(w4[p][kq].y),
                             "+v"(w4[p][kq].z), "+v"(w4[p][kq].w));

    // cell role: tid<64 owns (u = tid>>2, b = tid&3)
    const int uu = (tid & 63) >> 2;
    const int cb = tid & 3;
    float bias4[4];
#pragma unroll
    for (int gt = 0; gt < 4; gt++) {
        int R = gt * HDIM + UNITS * j + uu;
        bias4[gt] = b_ih[R] + b_hh[R];
    }
    float c_reg = 0.0f;

    const int swz = (kh & 3) << 2;      // pass-B read swizzle

    unsigned long long* const T0 = htag + (size_t)g * HT_GROUP;            // parity 0
    unsigned long long* const T1 = htag + HT_PAR + (size_t)g * HT_GROUP;   // parity 1

    __syncthreads();

    for (int s = 0; s < SEQL; s++) {
        const unsigned long long* Tin = (s & 1) ? T1 : T0;
        unsigned long long*       Tout = (s & 1) ? T0 : T1;
        const int exb = EX_OFF + (s & 1) * EX_PAR;

        // ---- (0) prefetch input-proj gates (non-temporal stream) ----
        float gp[4] = {0.f, 0.f, 0.f, 0.f};
        if (pre && tid < 64) {
            const float* gbase = gates + (size_t)(s * GROUPS + g) * 8192 + 64 * j;
#pragma unroll
            for (int gt = 0; gt < 4; gt++)
                gp[gt] = __builtin_nontemporal_load(gbase + gt * 2048 + tid);
        }

        float acc[4][4];
#pragma unroll
        for (int p = 0; p < 4; p++)
#pragma unroll
            for (int b = 0; b < 4; b++) acc[p][b] = 0.f;

        // ---- (1) fallback pass A (cold path; pre-path skips) ----
        if (!pre) {
            for (int i = tid; i < EDIM * GB; i += TPB) {
                int e = i >> 2, b = i & 3;
                int row = x[(GB * g + b) * SEQL + s];
                lds[EMB_OFF + i] = emb[(size_t)row * EDIM + e];
            }
            __syncthreads();
            if (kh < 15) {
                for (int e = 20 * kh; e < 20 * kh + 20; e++) {
                    float4 e0 = *(const float4*)&lds[EMB_OFF + 4 * e];
#pragma unroll
                    for (int p = 0; p < 4; p++) {
                        const int r = 4 * rq + p;
                        const size_t R = (size_t)((r >> 4) * HDIM + UNITS * j + (r & 15));
                        float wc = W_ih[R * EDIM + e];
                        acc[p][0] = fmaf(wc, e0.x, acc[p][0]);
                        acc[p][1] = fmaf(wc, e0.y, acc[p][1]);
                        acc[p][2] = fmaf(wc, e0.z, acc[p][2]);
                        acc[p][3] = fmaf(wc, e0.w, acc[p][3]);
                    }
                }
            }
            __syncthreads();
        }

        // ---- (2) WAVE-LOCAL single-sweep poll (8 words), then stage ----
        {
            const unsigned tag = (unsigned)s;
            unsigned long long d[8];
            const int vi0 = 4 * (128 * wv + ln);
            const int vi1 = 4 * (128 * wv + 64 + ln);
            for (;;) {
#pragma unroll
                for (int q = 0; q < 4; q++) {
                    d[q]     = __hip_atomic_load(Tin + vi0 + q, __ATOMIC_RELAXED, __HIP_MEMORY_SCOPE_AGENT);
                    d[4 + q] = __hip_atomic_load(Tin + vi1 + q, __ATOMIC_RELAXED, __HIP_MEMORY_SCOPE_AGENT);
                }
                bool ok = true;
#pragma unroll
                for (int w8 = 0; w8 < 8; w8++)
                    ok &= ((unsigned)(d[w8] >> 32) == tag);
                if (ok) break;
                __builtin_amdgcn_s_sleep(1);
            }
#pragma unroll
            for (int rr = 0; rr < 2; rr++) {
                const int k = 128 * wv + 64 * rr + ln;
                const int phys = (4 * k) ^ (((k >> 5) & 3) << 2);
                float4 hv;
                hv.x = __uint_as_float((unsigned)d[4 * rr + 0]);
                hv.y = __uint_as_float((unsigned)d[4 * rr + 1]);
                hv.z = __uint_as_float((unsigned)d[4 * rr + 2]);
                hv.w = __uint_as_float((unsigned)d[4 * rr + 3]);
                *(float4*)&lds[phys] = hv;
            }
        }
        asm volatile("" ::: "memory");
        __builtin_amdgcn_sched_barrier(0);

        // ---- (3) pass B: W_hh regs x h LDS (conflict-free reads) ----
#pragma unroll
        for (int kq = 0; kq < 8; kq++) {
#pragma unroll
            for (int ki = 0; ki < 4; ki++) {
                const int kidx = 4 * kq + ki;
                const float4 h0 = *(const float4*)&lds[128 * kh + ((4 * kidx) ^ swz)];
#pragma unroll
                for (int p = 0; p < 4; p++) {
                    const float4 wvv = w4[p][kq];
                    const float wc = ki == 0 ? wvv.x : ki == 1 ? wvv.y
                                   : ki == 2 ? wvv.z : wvv.w;
                    acc[p][0] = fmaf(wc, h0.x, acc[p][0]);
                    acc[p][1] = fmaf(wc, h0.y, acc[p][1]);
                    acc[p][2] = fmaf(wc, h0.z, acc[p][2]);
                    acc[p][3] = fmaf(wc, h0.w, acc[p][3]);
                }
            }
        }

        // ---- (4) exchange k-partials: ex[par][r][b][kh] ----
#pragma unroll
        for (int p = 0; p < 4; p++) {
            const int base = exb + (4 * rq + p) * EX_RSTR + kh;
#pragma unroll
            for (int b = 0; b < 4; b++)
                lds[base + b * EX_BSTR] = acc[p][b];
        }
        __syncthreads();   // B1: ex(par) visible to cell readers

        // ---- (5) cell update + tagged store (tid<64 owns (u, b)) ----
        if (tid < 64) {
            float gs[4];
#pragma unroll
            for (int gt = 0; gt < 4; gt++) {
                float sum = bias4[gt] + gp[gt];
                const int base = exb + (gt * 16 + uu) * EX_RSTR + cb * EX_BSTR;
#pragma unroll
                for (int kk = 0; kk < 16; kk++) sum += lds[base + kk];
                gs[gt] = sum;
            }
            float iv = fast_sigmoid(gs[0]);
            float fv = fast_sigmoid(gs[1]);
            float gv = fast_tanh(gs[2]);
            float ov = fast_sigmoid(gs[3]);
            c_reg = fv * c_reg + iv * gv;
            float hv = ov * fast_tanh(c_reg);
            unsigned long long wword =
                ((unsigned long long)(unsigned)(s + 1) << 32) |
                (unsigned long long)__float_as_uint(hv);
            __hip_atomic_store(Tout + 64 * j + tid, wword,
                               __ATOMIC_RELAXED, __HIP_MEMORY_SCOPE_AGENT);
        }
        // NO B2: ex is parity-buffered. Any wave's ex-write(s+2, this parity)
        // is behind B1(s+1), which wave 0 reaches only after cell-read(s).
    }
}

// FC head + softmax. Final h: parity 0 (SEQL even); value = lo32.
extern "C" __global__ void __launch_bounds__(320)
lstm_epilogue(const unsigned long long* __restrict__ htag,
              const float* __restrict__ W_fc, const float* __restrict__ b_fc,
              float* __restrict__ out)
{
    __shared__ float sl[ODIM * BATCH];
    const int t = threadIdx.x;
    {
        int o = t / BATCH, b = t - o * BATCH;
        const unsigned long long* hb = htag + (size_t)(b >> 2) * HT_GROUP;
        const int bc = b & 3;
        float acc = b_fc[o];
        const float4* wv = (const float4*)(W_fc + o * HDIM);
#pragma unroll 8
        for (int k4 = 0; k4 < HDIM / 4; k4++) {
            float4 w = wv[k4];
            const int k0 = 4 * k4;
            acc = fmaf(__uint_as_float((unsigned)hb[(k0 + 0) * 4 + bc]), w.x, acc);
            acc = fmaf(__uint_as_float((unsigned)hb[(k0 + 1) * 4 + bc]), w.y, acc);
            acc = fmaf(__uint_as_float((unsigned)hb[(k0 + 2) * 4 + bc]), w.z, acc);
            acc = fmaf(__uint_as_float((unsigned)hb[(k0 + 3) * 4 + bc]), w.w, acc);
        }
        sl[o * BATCH + b] = acc;
    }
    __syncthreads();
    if (t < BATCH) {
        float l0 = sl[t], l1 = sl[BATCH + t], l2 = sl[2 * BATCH + t];
        float l3 = sl[3 * BATCH + t], l4 = sl[4 * BATCH + t];
        float m = fmaxf(fmaxf(fmaxf(l0, l1), fmaxf(l2, l3)), l4);
        float e0 = __expf(l0 - m), e1 = __expf(l1 - m), e2 = __expf(l2 - m);
        float e3 = __expf(l3 - m), e4 = __expf(l4 - m);
        float inv = 1.0f / (e0 + e1 + e2 + e3 + e4);
        out[t * ODIM + 0] = e0 * inv;
        out[t * ODIM + 1] = e1 * inv;
        out[t * ODIM + 2] = e2 * inv;
        out[t * ODIM + 3] = e3 * inv;
        out[t * ODIM + 4] = e4 * inv;
    }
}

extern "C" void kernel_launch(void* const* d_in, const int* in_sizes, int n_in,
                              void* d_out, int out_size, void* d_ws, size_t ws_size,
                              hipStream_t stream)
{
    const int*   x    = (const int*)d_in[0];
    const float* emb  = (const float*)d_in[1];
    const float* W_ih = (const float*)d_in[2];
    const float* W_hh = (const float*)d_in[3];
    const float* b_ih = (const float*)d_in[4];
    const float* b_hh = (const float*)d_in[5];
    const float* W_fc = (const float*)d_in[6];
    const float* b_fc = (const float*)d_in[7];
    float* out = (float*)d_out;

    // ws layout: [htag 512 KiB][gates 104.9 MB (optional)][W_ihT 2.4 MB (optional)]
    unsigned long long* htag = (unsigned long long*)d_ws;
    const size_t gates_bytes = GATES_FLOATS * sizeof(float);
    const size_t wt_bytes    = WT_FLOATS * sizeof(float);
    float* gates = nullptr;
    float* wT    = nullptr;
    if (ws_size >= (size_t)HT_BYTES + gates_bytes) {
        gates = (float*)((char*)d_ws + HT_BYTES);
        if (ws_size >= (size_t)HT_BYTES + gates_bytes + wt_bytes)
            wT = (float*)((char*)d_ws + HT_BYTES + gates_bytes);
    }

    (void)hipMemsetAsync(htag, 0, HT_BYTES, stream);   // tag 0 / h = 0 for step 0

    (void)hipFuncSetAttribute((const void*)lstm_persist,
                              hipFuncAttributeMaxDynamicSharedMemorySize, LDS_BYTES);
    if (gates) {
        (void)hipFuncSetAttribute((const void*)lstm_pre,
                                  hipFuncAttributeMaxDynamicSharedMemorySize, PRE_LDS_BYTES);
        if (wT) {
            dim3 tg(NROW / 32, (EDIM + 31) / 32);
            wih_transpose<<<tg, 256, 0, stream>>>(W_ih, wT);
        }
        lstm_pre<<<SEQL * 16, 256, PRE_LDS_BYTES, stream>>>(x, emb, W_ih, wT, gates);
    }

    lstm_persist<<<NWG, TPB, LDS_BYTES, stream>>>(x, emb, W_ih, W_hh, b_ih, b_hh,
                                                  gates, htag);

    lstm_epilogue<<<1, 320, 0, stream>>>(htag, W_fc, b_fc, out);
}

// Round 18
// 1436.579 us; speedup vs baseline: 1.0730x; 1.0730x over previous
//
#include <hip/hip_runtime.h>

// ---------------- problem constants ----------------
#define TPB   256
#define NWG   512
#define SEQL  200
#define BATCH 64
#define EDIM  300
#define HDIM  512
#define ODIM  5
#define NROW  (4*HDIM)   // 2048 gate rows

// ---------------- group decomposition ----------------
#define GROUPS 16     // independent batch groups (group = blockIdx & 15)
#define GB     4      // batch rows per group
#define UNITS  16     // h units per block

// ---------------- persist-kernel LDS layout (word offsets) — r12 verbatim ----
#define EX_OFF   2048
#define EX_RSTR  69
#define EX_BSTR  17
#define EMB_OFF  (EX_OFF + 64*EX_RSTR)       // 6464
#define LDS_BYTES 56320                      // 55 KiB: 2 blocks/CU fit, 3 don't

// ---------------- tagged h exchange ----------------
#define HT_GROUP 2048
#define HT_PAR   (GROUPS * HT_GROUP)               // 32768 ull per parity
#define HT_BYTES (2 * HT_PAR * 8)                  // 512 KiB

// ---------------- precompute-kernel LDS (half-batch: 32 rows) ----------------
#define ESTR 308
#define PRE_LDS_BYTES (32 * ESTR * 4)        // 39424 B -> 4 blocks/CU

#define GATES_FLOATS ((size_t)SEQL * NROW * BATCH)   // 104.9 MB
#define WT_FLOATS    ((size_t)EDIM * NROW)           // 614400 (2.4 MB)

__device__ __forceinline__ float fast_sigmoid(float x) {
    return 1.0f / (1.0f + __expf(-x));
}
__device__ __forceinline__ float fast_tanh(float x) {
    return 2.0f / (1.0f + __expf(-2.0f * x)) - 1.0f;
}

// ============================================================================
// W_ih transpose: WT[e][row] = W_ih[row][e].  Tiled 32x32 via LDS.
// ============================================================================
extern "C" __global__ void __launch_bounds__(256)
wih_transpose(const float* __restrict__ W, float* __restrict__ WT)
{
    __shared__ float t[32][33];
    const int r0 = blockIdx.x * 32;
    const int e0 = blockIdx.y * 32;
    const int le = threadIdx.x & 31;
    const int lr = threadIdx.x >> 5;

    for (int rr = lr; rr < 32; rr += 8) {
        const int e = e0 + le;
        t[rr][le] = (e < EDIM) ? W[(size_t)(r0 + rr) * EDIM + e] : 0.0f;
    }
    __syncthreads();
    for (int ee = lr; ee < 32; ee += 8) {
        const int e = e0 + ee;
        if (e < EDIM) WT[(size_t)e * NROW + r0 + le] = t[le][ee];
    }
}

// ============================================================================
// Precompute: gates[s][group][row][4]. Half-batch blocks: 32 batch rows,
// 39.4 KB LDS -> 4 blocks/CU. Thread tile: 4 rows x 8 batch. WT loads
// coalesced; emb LDS reads wave-uniform broadcast (bi = tid>>6).
// grid = 200 s x 8 rb x 2 half.
// ============================================================================
extern "C" __global__ void __launch_bounds__(256, 4)
lstm_pre(const int* __restrict__ x, const float* __restrict__ emb,
         const float* __restrict__ W_ih, const float* __restrict__ wT,
         float* __restrict__ gates)
{
    extern __shared__ float embs[];          // [32][ESTR]
    const int tid = threadIdx.x;
    const int s   = blockIdx.x >> 4;
    const int rb  = (blockIdx.x >> 1) & 7;
    const int hb  = blockIdx.x & 1;          // batch half

    for (int i = tid; i < 32 * 75; i += 256) {
        int b = i / 75, jj = i - b * 75;
        int row = x[(32 * hb + b) * SEQL + s];
        float4 v = ((const float4*)(emb + (size_t)row * EDIM))[jj];
        *(float4*)&embs[b * ESTR + 4 * jj] = v;
    }
    __syncthreads();

    const int bi = tid >> 6;      // octet within half (0..3) — wave-uniform
    const int ri = tid & 63;
    const int row0 = rb * 256 + ri * 4;

    float acc[4][8];
#pragma unroll
    for (int a = 0; a < 4; a++)
#pragma unroll
        for (int b = 0; b < 8; b++) acc[a][b] = 0.0f;

    if (wT) {
        for (int t2 = 0; t2 < 75; t2++) {
            float4 w[4], e[8];
#pragma unroll
            for (int c = 0; c < 4; c++)
                w[c] = *(const float4*)(wT + (size_t)(4 * t2 + c) * NROW + row0);
#pragma unroll
            for (int bb = 0; bb < 8; bb++)
                e[bb] = *(const float4*)&embs[(bi * 8 + bb) * ESTR + 4 * t2];
#pragma unroll
            for (int c = 0; c < 4; c++) {
#pragma unroll
                for (int bb = 0; bb < 8; bb++) {
                    const float ec = c == 0 ? e[bb].x : c == 1 ? e[bb].y
                                   : c == 2 ? e[bb].z : e[bb].w;
                    acc[0][bb] = fmaf(w[c].x, ec, acc[0][bb]);
                    acc[1][bb] = fmaf(w[c].y, ec, acc[1][bb]);
                    acc[2][bb] = fmaf(w[c].z, ec, acc[2][bb]);
                    acc[3][bb] = fmaf(w[c].w, ec, acc[3][bb]);
                }
            }
        }
    } else {
        const float* wp = W_ih + (size_t)row0 * EDIM;
        for (int t2 = 0; t2 < 75; t2++) {
            float4 w[4], e[8];
#pragma unroll
            for (int rr = 0; rr < 4; rr++)
                w[rr] = *(const float4*)(wp + rr * EDIM + 4 * t2);
#pragma unroll
            for (int bb = 0; bb < 8; bb++)
                e[bb] = *(const float4*)&embs[(bi * 8 + bb) * ESTR + 4 * t2];
#pragma unroll
            for (int rr = 0; rr < 4; rr++)
#pragma unroll
                for (int bb = 0; bb < 8; bb++) {
                    acc[rr][bb] = fmaf(w[rr].x, e[bb].x, acc[rr][bb]);
                    acc[rr][bb] = fmaf(w[rr].y, e[bb].y, acc[rr][bb]);
                    acc[rr][bb] = fmaf(w[rr].z, e[bb].z, acc[rr][bb]);
                    acc[rr][bb] = fmaf(w[rr].w, e[bb].w, acc[rr][bb]);
                }
        }
    }

    float* dstA = gates + (size_t)(s * GROUPS + 8 * hb + 2 * bi)     * 8192 + row0 * 4;
    float* dstB = gates + (size_t)(s * GROUPS + 8 * hb + 2 * bi + 1) * 8192 + row0 * 4;
#pragma unroll
    for (int rr = 0; rr < 4; rr++) {
        *(float4*)(dstA + 4 * rr) = make_float4(acc[rr][0], acc[rr][1], acc[rr][2], acc[rr][3]);
        *(float4*)(dstB + 4 * rr) = make_float4(acc[rr][4], acc[rr][5], acc[rr][6], acc[rr][7]);
    }
}

// ============================================================================
// Persistent LSTM — r12 VERBATIM (best measured: ~1175 us).
// ============================================================================
extern "C" __global__ void __launch_bounds__(TPB, 2)
lstm_persist(const int* __restrict__ x, const float* __restrict__ emb,
             const float* __restrict__ W_ih, const float* __restrict__ W_hh,
             const float* __restrict__ b_ih, const float* __restrict__ b_hh,
             const float* __restrict__ gates,      // may be null
             unsigned long long* __restrict__ htag) // [2][16][2048] tagged h
{
    extern __shared__ float lds[];
    const int tid = threadIdx.x;
    const int g   = blockIdx.x & 15;
    const int j   = blockIdx.x >> 4;        // 0..31
    const bool pre = (gates != nullptr);

    const int rq = tid & 15;      // rows 4rq..4rq+3 (r = gate*16+u)
    const int kh = tid >> 4;      // k in [32kh, 32kh+32)
    const int wv = tid >> 6;      // wave 0..3
    const int ln = tid & 63;      // lane

    // ---- W_hh slice -> 128 VGPRs (static indexing only; rule #20) ----
    float4 w4[4][8];
#pragma unroll
    for (int p = 0; p < 4; p++) {
        const int r = 4 * rq + p;
        const size_t R = (size_t)((r >> 4) * HDIM + UNITS * j + (r & 15));
        const float* wp = W_hh + R * HDIM + 32 * kh;
#pragma unroll
        for (int kq = 0; kq < 8; kq++) w4[p][kq] = *(const float4*)(wp + 4 * kq);
    }
#pragma unroll
    for (int p = 0; p < 4; p++)
#pragma unroll
        for (int kq = 0; kq < 8; kq++)
            asm volatile("" : "+v"(w4[p][kq].x), "+v"(w4[p][kq].y),
                             "+v"(w4[p][kq].z), "+v"(w4[p][kq].w));

    // cell role: tid<64 owns (u = tid>>2, b = tid&3)
    const int uu = (tid & 63) >> 2;
    const int cb = tid & 3;
    float bias4[4];
#pragma unroll
    for (int gt = 0; gt < 4; gt++) {
        int R = gt * HDIM + UNITS * j + uu;
        bias4[gt] = b_ih[R] + b_hh[R];
    }
    float c_reg = 0.0f;

    const int swz = (kh & 3) << 2;      // pass-B read swizzle

    unsigned long long* const T0 = htag + (size_t)g * HT_GROUP;            // parity 0
    unsigned long long* const T1 = htag + HT_PAR + (size_t)g * HT_GROUP;   // parity 1

    __syncthreads();

    for (int s = 0; s < SEQL; s++) {
        const unsigned long long* Tin = (s & 1) ? T1 : T0;
        unsigned long long*       Tout = (s & 1) ? T0 : T1;

        // ---- (0) prefetch input-proj gates (non-temporal stream) ----
        float gp[4] = {0.f, 0.f, 0.f, 0.f};
        if (pre && tid < 64) {
            const float* gbase = gates + (size_t)(s * GROUPS + g) * 8192 + 64 * j;
#pragma unroll
            for (int gt = 0; gt < 4; gt++)
                gp[gt] = __builtin_nontemporal_load(gbase + gt * 2048 + tid);
        }

        float acc[4][4];
#pragma unroll
        for (int p = 0; p < 4; p++)
#pragma unroll
            for (int b = 0; b < 4; b++) acc[p][b] = 0.f;

        // ---- (1) fallback pass A (cold path; pre-path skips) ----
        if (!pre) {
            for (int i = tid; i < EDIM * GB; i += TPB) {
                int e = i >> 2, b = i & 3;
                int row = x[(GB * g + b) * SEQL + s];
                lds[EMB_OFF + i] = emb[(size_t)row * EDIM + e];
            }
            __syncthreads();
            if (kh < 15) {
                for (int e = 20 * kh; e < 20 * kh + 20; e++) {
                    float4 e0 = *(const float4*)&lds[EMB_OFF + 4 * e];
#pragma unroll
                    for (int p = 0; p < 4; p++) {
                        const int r = 4 * rq + p;
                        const size_t R = (size_t)((r >> 4) * HDIM + UNITS * j + (r & 15));
                        float wc = W_ih[R * EDIM + e];
                        acc[p][0] = fmaf(wc, e0.x, acc[p][0]);
                        acc[p][1] = fmaf(wc, e0.y, acc[p][1]);
                        acc[p][2] = fmaf(wc, e0.z, acc[p][2]);
                        acc[p][3] = fmaf(wc, e0.w, acc[p][3]);
                    }
                }
            }
            __syncthreads();
        }

        // ---- (2) WAVE-LOCAL poll+stage: rows k = 128*wv + {0,64} + ln ----
        {
            const unsigned tag = (unsigned)s;
#pragma unroll
            for (int rr = 0; rr < 2; rr++) {
                const int k = 128 * wv + 64 * rr + ln;
                const int vi = 4 * k;
                unsigned long long d0, d1, d2, d3;
                for (;;) {
                    d0 = __hip_atomic_load(Tin + vi + 0, __ATOMIC_RELAXED, __HIP_MEMORY_SCOPE_AGENT);
                    d1 = __hip_atomic_load(Tin + vi + 1, __ATOMIC_RELAXED, __HIP_MEMORY_SCOPE_AGENT);
                    d2 = __hip_atomic_load(Tin + vi + 2, __ATOMIC_RELAXED, __HIP_MEMORY_SCOPE_AGENT);
                    d3 = __hip_atomic_load(Tin + vi + 3, __ATOMIC_RELAXED, __HIP_MEMORY_SCOPE_AGENT);
                    if ((unsigned)(d0 >> 32) == tag && (unsigned)(d1 >> 32) == tag &&
                        (unsigned)(d2 >> 32) == tag && (unsigned)(d3 >> 32) == tag)
                        break;
                    __builtin_amdgcn_s_sleep(1);
                }
                const int phys = (4 * k) ^ (((k >> 5) & 3) << 2);
                float4 hv;
                hv.x = __uint_as_float((unsigned)d0);
                hv.y = __uint_as_float((unsigned)d1);
                hv.z = __uint_as_float((unsigned)d2);
                hv.w = __uint_as_float((unsigned)d3);
                *(float4*)&lds[phys] = hv;
            }
        }
        asm volatile("" ::: "memory");
        __builtin_amdgcn_sched_barrier(0);

        // ---- (3) pass B: W_hh regs x h LDS (conflict-free reads) ----
#pragma unroll
        for (int kq = 0; kq < 8; kq++) {
#pragma unroll
            for (int ki = 0; ki < 4; ki++) {
                const int kidx = 4 * kq + ki;
                const float4 h0 = *(const float4*)&lds[128 * kh + ((4 * kidx) ^ swz)];
#pragma unroll
                for (int p = 0; p < 4; p++) {
                    const float4 wvv = w4[p][kq];
                    const float wc = ki == 0 ? wvv.x : ki == 1 ? wvv.y
                                   : ki == 2 ? wvv.z : wvv.w;
                    acc[p][0] = fmaf(wc, h0.x, acc[p][0]);
                    acc[p][1] = fmaf(wc, h0.y, acc[p][1]);
                    acc[p][2] = fmaf(wc, h0.z, acc[p][2]);
                    acc[p][3] = fmaf(wc, h0.w, acc[p][3]);
                }
            }
        }

        // ---- (4) exchange k-partials: ex[r][b][kh] ----
#pragma unroll
        for (int p = 0; p < 4; p++) {
            const int base = EX_OFF + (4 * rq + p) * EX_RSTR + kh;
#pragma unroll
            for (int b = 0; b < 4; b++)
                lds[base + b * EX_BSTR] = acc[p][b];
        }
        __syncthreads();   // B1: all ex writes visible to cell readers

        // ---- (5) cell update + tagged store (tid<64 owns (u, b)) ----
        if (tid < 64) {
            float gs[4];
#pragma unroll
            for (int gt = 0; gt < 4; gt++) {
                float sum = bias4[gt] + gp[gt];
                const int base = EX_OFF + (gt * 16 + uu) * EX_RSTR + cb * EX_BSTR;
#pragma unroll
                for (int kk = 0; kk < 16; kk++) sum += lds[base + kk];
                gs[gt] = sum;
            }
            float iv = fast_sigmoid(gs[0]);
            float fv = fast_sigmoid(gs[1]);
            float gv = fast_tanh(gs[2]);
            float ov = fast_sigmoid(gs[3]);
            c_reg = fv * c_reg + iv * gv;
            float hv = ov * fast_tanh(c_reg);
            unsigned long long wword =
                ((unsigned long long)(unsigned)(s + 1) << 32) |
                (unsigned long long)__float_as_uint(hv);
            __hip_atomic_store(Tout + 64 * j + tid, wword,
                               __ATOMIC_RELAXED, __HIP_MEMORY_SCOPE_AGENT);
        }
        __syncthreads();   // B2: cell reads done before next step's ex writes
    }
}

// FC head + softmax. Final h: parity 0 (SEQL even); value = lo32.
extern "C" __global__ void __launch_bounds__(320)
lstm_epilogue(const unsigned long long* __restrict__ htag,
              const float* __restrict__ W_fc, const float* __restrict__ b_fc,
              float* __restrict__ out)
{
    __shared__ float sl[ODIM * BATCH];
    const int t = threadIdx.x;
    {
        int o = t / BATCH, b = t - o * BATCH;
        const unsigned long long* hb = htag + (size_t)(b >> 2) * HT_GROUP;
        const int bc = b & 3;
        float acc = b_fc[o];
        const float4* wv = (const float4*)(W_fc + o * HDIM);
#pragma unroll 8
        for (int k4 = 0; k4 < HDIM / 4; k4++) {
            float4 w = wv[k4];
            const int k0 = 4 * k4;
            acc = fmaf(__uint_as_float((unsigned)hb[(k0 + 0) * 4 + bc]), w.x, acc);
            acc = fmaf(__uint_as_float((unsigned)hb[(k0 + 1) * 4 + bc]), w.y, acc);
            acc = fmaf(__uint_as_float((unsigned)hb[(k0 + 2) * 4 + bc]), w.z, acc);
            acc = fmaf(__uint_as_float((unsigned)hb[(k0 + 3) * 4 + bc]), w.w, acc);
        }
        sl[o * BATCH + b] = acc;
    }
    __syncthreads();
    if (t < BATCH) {
        float l0 = sl[t], l1 = sl[BATCH + t], l2 = sl[2 * BATCH + t];
        float l3 = sl[3 * BATCH + t], l4 = sl[4 * BATCH + t];
        float m = fmaxf(fmaxf(fmaxf(l0, l1), fmaxf(l2, l3)), l4);
        float e0 = __expf(l0 - m), e1 = __expf(l1 - m), e2 = __expf(l2 - m);
        float e3 = __expf(l3 - m), e4 = __expf(l4 - m);
        float inv = 1.0f / (e0 + e1 + e2 + e3 + e4);
        out[t * ODIM + 0] = e0 * inv;
        out[t * ODIM + 1] = e1 * inv;
        out[t * ODIM + 2] = e2 * inv;
        out[t * ODIM + 3] = e3 * inv;
        out[t * ODIM + 4] = e4 * inv;
    }
}

extern "C" void kernel_launch(void* const* d_in, const int* in_sizes, int n_in,
                              void* d_out, int out_size, void* d_ws, size_t ws_size,
                              hipStream_t stream)
{
    const int*   x    = (const int*)d_in[0];
    const float* emb  = (const float*)d_in[1];
    const float* W_ih = (const float*)d_in[2];
    const float* W_hh = (const float*)d_in[3];
    const float* b_ih = (const float*)d_in[4];
    const float* b_hh = (const float*)d_in[5];
    const float* W_fc = (const float*)d_in[6];
    const float* b_fc = (const float*)d_in[7];
    float* out = (float*)d_out;

    // ws layout: [htag 512 KiB][gates 104.9 MB (optional)][W_ihT 2.4 MB (optional)]
    unsigned long long* htag = (unsigned long long*)d_ws;
    const size_t gates_bytes = GATES_FLOATS * sizeof(float);
    const size_t wt_bytes    = WT_FLOATS * sizeof(float);
    float* gates = nullptr;
    float* wT    = nullptr;
    if (ws_size >= (size_t)HT_BYTES + gates_bytes) {
        gates = (float*)((char*)d_ws + HT_BYTES);
        if (ws_size >= (size_t)HT_BYTES + gates_bytes + wt_bytes)
            wT = (float*)((char*)d_ws + HT_BYTES + gates_bytes);
    }

    (void)hipMemsetAsync(htag, 0, HT_BYTES, stream);   // tag 0 / h = 0 for step 0

    (void)hipFuncSetAttribute((const void*)lstm_persist,
                              hipFuncAttributeMaxDynamicSharedMemorySize, LDS_BYTES);
    if (gates) {
        (void)hipFuncSetAttribute((const void*)lstm_pre,
                                  hipFuncAttributeMaxDynamicSharedMemorySize, PRE_LDS_BYTES);
        if (wT) {
            dim3 tg(NROW / 32, (EDIM + 31) / 32);
            wih_transpose<<<tg, 256, 0, stream>>>(W_ih, wT);
        }
        lstm_pre<<<SEQL * 16, 256, PRE_LDS_BYTES, stream>>>(x, emb, W_ih, wT, gates);
    }

    lstm_persist<<<NWG, TPB, LDS_BYTES, stream>>>(x, emb, W_ih, W_hh, b_ih, b_hh,
                                                  gates, htag);

    lstm_epilogue<<<1, 320, 0, stream>>>(htag, W_fc, b_fc, out);
}